// Round 2
// baseline (325.173 us; speedup 1.0000x reference)
//
#include <hip/hip_runtime.h>
#include <hip/hip_bf16.h>
#include <math.h>

typedef unsigned short u16;
typedef unsigned int u32;
typedef __bf16 bf16x8 __attribute__((ext_vector_type(8)));
typedef float fx4 __attribute__((ext_vector_type(4)));

#define MFMA16(a, b, c) __builtin_amdgcn_mfma_f32_16x16x32_bf16(a, b, c, 0, 0, 0)

static constexpr int Bb = 2, Ss = 2048, Dd = 1024, Hh = 16, HDd = 64, DKV = 256;
static constexpr int ROWS = Bb * Ss; // 4096

__device__ inline u16 f2bf(float f) {
    union { float f; u32 i; } v; v.f = f;
    u32 u = v.i;
    u32 r = (u + 0x7FFFu + ((u >> 16) & 1u)) >> 16;
    return (u16)r;
}

// ---------------- prep: f32 x -> bf16 xc (NaN->0), key_pad flag ----------------
__global__ void prep_kernel(const float* __restrict__ x, u16* __restrict__ xc,
                            u32* __restrict__ kp) {
    int row = blockIdx.x;
    int t = threadIdx.x;
    __shared__ int flag;
    if (t == 0) flag = 0;
    __syncthreads();
    float4 d = *(const float4*)(x + (size_t)row * Dd + t * 4);
    int any = 0;
    float a0 = d.x, a1 = d.y, a2 = d.z, a3 = d.w;
    // bit-test NaN (safe under fast-math)
    if ((__float_as_uint(a0) & 0x7FFFFFFFu) > 0x7F800000u) { a0 = 0.f; any = 1; }
    if ((__float_as_uint(a1) & 0x7FFFFFFFu) > 0x7F800000u) { a1 = 0.f; any = 1; }
    if ((__float_as_uint(a2) & 0x7FFFFFFFu) > 0x7F800000u) { a2 = 0.f; any = 1; }
    if ((__float_as_uint(a3) & 0x7FFFFFFFu) > 0x7F800000u) { a3 = 0.f; any = 1; }
    if (any) atomicOr(&flag, 1);
    uint2 o;
    o.x = (u32)f2bf(a0) | ((u32)f2bf(a1) << 16);
    o.y = (u32)f2bf(a2) | ((u32)f2bf(a3) << 16);
    *(uint2*)(xc + (size_t)row * Dd + t * 4) = o;
    __syncthreads();
    if (t == 0) kp[row] = (u32)flag;
}

// ------------- transpose f32 (R x C) -> bf16 (C x R) -------------
__global__ void transpose_kernel(const float* __restrict__ in, u16* __restrict__ out,
                                 int R, int C) {
    __shared__ u16 tile[32][33];
    int c0 = blockIdx.x * 32, r0 = blockIdx.y * 32;
    int tx = threadIdx.x & 31, ty = threadIdx.x >> 5; // 256 thr: ty 0..7
    for (int i = 0; i < 32; i += 8)
        tile[ty + i][tx] = f2bf(in[(size_t)(r0 + ty + i) * C + c0 + tx]);
    __syncthreads();
    for (int i = 0; i < 32; i += 8)
        out[(size_t)(c0 + ty + i) * R + r0 + tx] = tile[tx][ty + i];
}

// v_small (per b: S x 256 bf16) -> v_t (per b: 256 x S bf16)
__global__ void vtrans_kernel(const u16* __restrict__ in, u16* __restrict__ out) {
    __shared__ u16 tile[32][33];
    int b = blockIdx.z;
    const u16* I = in + (size_t)b * Ss * DKV;
    u16* O = out + (size_t)b * DKV * Ss;
    int c0 = blockIdx.x * 32, r0 = blockIdx.y * 32; // r over s, c over f
    int tx = threadIdx.x & 31, ty = threadIdx.x >> 5;
    for (int i = 0; i < 32; i += 8)
        tile[ty + i][tx] = I[(size_t)(r0 + ty + i) * DKV + c0 + tx];
    __syncthreads();
    for (int i = 0; i < 32; i += 8)
        O[(size_t)(c0 + ty + i) * Ss + r0 + tx] = tile[tx][ty + i];
}

// ---------------- GEMM: C[M,N] = A[M,K] * Bt[N,K]^T, all bf16 ----------------
__global__ __launch_bounds__(256) void gemm_tn_kernel(
    const u16* __restrict__ A, const u16* __restrict__ Bt, u16* __restrict__ C,
    int M, int N, int K) {
    __shared__ __align__(16) u16 As[128 * 40];
    __shared__ __align__(16) u16 Bs[128 * 40];
    int t = threadIdx.x;
    int col0 = blockIdx.x * 128, row0 = blockIdx.y * 128;
    int w = t >> 6, lane = t & 63;
    int wm = w >> 1, wn = w & 1;
    int l15 = lane & 15, quad = lane >> 4;
    fx4 acc[4][4];
#pragma unroll
    for (int i = 0; i < 4; ++i)
#pragma unroll
        for (int j = 0; j < 4; ++j) acc[i][j] = (fx4){0.f, 0.f, 0.f, 0.f};

    const int nk = K >> 5;
    for (int kb = 0; kb < nk; ++kb) {
        int kbase = kb * 32;
#pragma unroll
        for (int i = 0; i < 2; ++i) {
            int s = i * 256 + t;
            int r = s >> 2, c = s & 3;
            *(uint4*)(As + r * 40 + c * 8) =
                *(const uint4*)(A + (size_t)(row0 + r) * K + kbase + c * 8);
            *(uint4*)(Bs + r * 40 + c * 8) =
                *(const uint4*)(Bt + (size_t)(col0 + r) * K + kbase + c * 8);
        }
        __syncthreads();
        bf16x8 af[4], bfr[4];
#pragma unroll
        for (int mi = 0; mi < 4; ++mi)
            af[mi] = *(const bf16x8*)(As + (wm * 64 + mi * 16 + l15) * 40 + quad * 8);
#pragma unroll
        for (int ni = 0; ni < 4; ++ni)
            bfr[ni] = *(const bf16x8*)(Bs + (wn * 64 + ni * 16 + l15) * 40 + quad * 8);
#pragma unroll
        for (int mi = 0; mi < 4; ++mi)
#pragma unroll
            for (int ni = 0; ni < 4; ++ni)
                acc[mi][ni] = MFMA16(af[mi], bfr[ni], acc[mi][ni]);
        __syncthreads();
    }
#pragma unroll
    for (int mi = 0; mi < 4; ++mi) {
        int rbase = row0 + wm * 64 + mi * 16 + quad * 4;
#pragma unroll
        for (int ni = 0; ni < 4; ++ni) {
            int ccol = col0 + wn * 64 + ni * 16 + l15;
#pragma unroll
            for (int r = 0; r < 4; ++r)
                C[(size_t)(rbase + r) * N + ccol] = f2bf(acc[mi][ni][r]);
        }
    }
}

// ---------------- RoPE ----------------
static constexpr float L2T_OVER = 0.0259525632f; // log2(10000)/512

__global__ void rope_q_kernel(u16* __restrict__ q) {
    int row = blockIdx.x, t = threadIdx.x;
    float pos = (float)(row & (Ss - 1));
    u16* p = q + (size_t)row * Dd + t * 4;
    uint2 d = *(const uint2*)p;
    float x0 = __uint_as_float(((u32)(d.x & 0xFFFF)) << 16);
    float x1 = __uint_as_float((d.x >> 16) << 16);
    float x2 = __uint_as_float(((u32)(d.y & 0xFFFF)) << 16);
    float x3 = __uint_as_float((d.y >> 16) << 16);
    float j0 = (float)(2 * t), j1 = j0 + 1.0f;
    float f0 = exp2f(-j0 * L2T_OVER);
    float f1 = exp2f(-j1 * L2T_OVER);
    float s0, c0, s1, c1;
    sincosf(pos * f0, &s0, &c0);
    sincosf(pos * f1, &s1, &c1);
    float r0 = x0 * c0 - x1 * s0, r1 = x0 * s0 + x1 * c0;
    float r2 = x2 * c1 - x3 * s1, r3 = x2 * s1 + x3 * c1;
    uint2 o;
    o.x = (u32)f2bf(r0) | ((u32)f2bf(r1) << 16);
    o.y = (u32)f2bf(r2) | ((u32)f2bf(r3) << 16);
    *(uint2*)p = o;
}

// k_small (rows x 256 bf16) -> k_rope (rows x 1024 bf16); pair j has x1=x2=k_small[j/2]
__global__ void rope_k_kernel(const u16* __restrict__ ks, u16* __restrict__ kr) {
    int row = blockIdx.x, t = threadIdx.x;
    float pos = (float)(row & (Ss - 1));
    float kv = __uint_as_float(((u32)ks[(size_t)row * DKV + t]) << 16);
    float j0 = (float)(2 * t), j1 = j0 + 1.0f;
    float f0 = exp2f(-j0 * L2T_OVER);
    float f1 = exp2f(-j1 * L2T_OVER);
    float s0, c0, s1, c1;
    sincosf(pos * f0, &s0, &c0);
    sincosf(pos * f1, &s1, &c1);
    float r0 = kv * c0 - kv * s0, r1 = kv * s0 + kv * c0;
    float r2 = kv * c1 - kv * s1, r3 = kv * s1 + kv * c1;
    uint2 o;
    o.x = (u32)f2bf(r0) | ((u32)f2bf(r1) << 16);
    o.y = (u32)f2bf(r2) | ((u32)f2bf(r3) << 16);
    *(uint2*)(kr + (size_t)row * Dd + t * 4) = o;
}

// ---------------- flash attention ----------------
// grid (S/64, H, B), block 256 (4 waves x 16 queries)
__global__ __launch_bounds__(256) void attn_kernel(
    const u16* __restrict__ q, const u16* __restrict__ k,
    const u16* __restrict__ vt, const u32* __restrict__ kp,
    float* __restrict__ out) {
    __shared__ __align__(16) u16 Ks[32 * 72];  // 32 keys x 64 dims, pad 8
    __shared__ __align__(16) u16 Vs[16 * 40];  // 16 feats x 32 keys, pad 8
    __shared__ __align__(16) u16 Ps[4][16 * 40]; // per-wave P tile, pad 8
    __shared__ u32 kps[32];

    int t = threadIdx.x;
    int w = t >> 6, lane = t & 63;
    int l15 = lane & 15, quad = lane >> 4;
    int q0 = blockIdx.x * 64, h = blockIdx.y, b = blockIdx.z;
    int qbase = q0 + w * 16 + quad * 4;

    const u16* qrow = q + ((size_t)(b * Ss + q0 + w * 16 + l15)) * Dd + h * 64;
    bf16x8 qf0 = *(const bf16x8*)(qrow + quad * 8);
    bf16x8 qf1 = *(const bf16x8*)(qrow + 32 + quad * 8);

    float m_run[4] = {-1e30f, -1e30f, -1e30f, -1e30f};
    float l_run[4] = {0.f, 0.f, 0.f, 0.f};
    fx4 oacc = (fx4){0.f, 0.f, 0.f, 0.f};

    const int nkb = (q0 + 64) >> 5;
    for (int kb = 0; kb < nkb; ++kb) {
        int k0 = kb << 5;
        __syncthreads(); // protect LDS reuse
        {
            int key = t >> 3, c = t & 7;
            *(uint4*)(Ks + key * 72 + c * 8) =
                *(const uint4*)(k + ((size_t)(b * Ss + k0 + key)) * Dd + h * 64 + c * 8);
        }
        if (t < 64) {
            int f = t >> 2, c = t & 3;
            *(uint4*)(Vs + f * 40 + c * 8) =
                *(const uint4*)(vt + ((size_t)(b * DKV + h * 16 + f)) * Ss + k0 + c * 8);
        }
        if (t < 32) kps[t] = kp[b * Ss + k0 + t];
        __syncthreads();

        // QK^T: two 16-key column tiles, K-dim 64 = 2 MFMAs each
        fx4 s0 = (fx4){0.f, 0.f, 0.f, 0.f}, s1 = (fx4){0.f, 0.f, 0.f, 0.f};
        bf16x8 kf00 = *(const bf16x8*)(Ks + l15 * 72 + quad * 8);
        bf16x8 kf01 = *(const bf16x8*)(Ks + l15 * 72 + 32 + quad * 8);
        bf16x8 kf10 = *(const bf16x8*)(Ks + (16 + l15) * 72 + quad * 8);
        bf16x8 kf11 = *(const bf16x8*)(Ks + (16 + l15) * 72 + 32 + quad * 8);
        s0 = MFMA16(qf0, kf00, s0);
        s0 = MFMA16(qf1, kf01, s0);
        s1 = MFMA16(qf0, kf10, s1);
        s1 = MFMA16(qf1, kf11, s1);

        bool pad0 = (kps[l15] != 0), pad1 = (kps[16 + l15] != 0);
        int kk0 = k0 + l15, kk1 = k0 + 16 + l15;
        float p0[4], p1[4], alpha[4];
#pragma unroll
        for (int r = 0; r < 4; ++r) {
            int qq = qbase + r;
            float v0 = (kk0 <= qq && !pad0) ? s0[r] * 0.125f : -1e9f;
            float v1 = (kk1 <= qq && !pad1) ? s1[r] * 0.125f : -1e9f;
            float mx = fmaxf(v0, v1);
#pragma unroll
            for (int off = 1; off < 16; off <<= 1)
                mx = fmaxf(mx, __shfl_xor(mx, off, 16));
            float mn = fmaxf(m_run[r], mx);
            float a = __expf(m_run[r] - mn);
            float e0 = __expf(v0 - mn), e1 = __expf(v1 - mn);
            float sum = e0 + e1;
#pragma unroll
            for (int off = 1; off < 16; off <<= 1)
                sum += __shfl_xor(sum, off, 16);
            l_run[r] = l_run[r] * a + sum;
            m_run[r] = mn;
            alpha[r] = a;
            p0[r] = e0;
            p1[r] = e1;
        }
#pragma unroll
        for (int r = 0; r < 4; ++r) {
            Ps[w][(quad * 4 + r) * 40 + l15] = f2bf(p0[r]);
            Ps[w][(quad * 4 + r) * 40 + 16 + l15] = f2bf(p1[r]);
        }
#pragma unroll
        for (int r = 0; r < 4; ++r) oacc[r] *= alpha[r];
        __syncthreads();
        bf16x8 pf = *(const bf16x8*)(Ps[w] + l15 * 40 + quad * 8);
        bf16x8 vf = *(const bf16x8*)(Vs + l15 * 40 + quad * 8);
        oacc = MFMA16(pf, vf, oacc);
    }

    // epilogue: out[b, q, h*64 + 4*u .. +3] = O_small[u], replicated x4 (f32)
#pragma unroll
    for (int r = 0; r < 4; ++r) {
        float val = oacc[r] / l_run[r];
        float4 o = {val, val, val, val};
        *(float4*)(out + ((size_t)(b * Ss + qbase + r)) * Dd + h * 64 + l15 * 4) = o;
    }
}

// ---------------- launch ----------------
extern "C" void kernel_launch(void* const* d_in, const int* in_sizes, int n_in,
                              void* d_out, int out_size, void* d_ws, size_t ws_size,
                              hipStream_t stream) {
    const float* x = (const float*)d_in[0];
    const float* Wq = (const float*)d_in[1];
    const float* Wk = (const float*)d_in[2];
    const float* Wv = (const float*)d_in[3];
    float* out = (float*)d_out;

    char* ws = (char*)d_ws;
    // layout (bytes). krope aliases xc (xc dead before rope_k). vtb aliases wqT.
    const size_t SZ_XC = (size_t)ROWS * Dd * 2;      // 8 MiB
    const size_t SZ_KP = (size_t)ROWS * 4;           // 16 KiB
    const size_t SZ_WQT = (size_t)Dd * Dd * 2;       // 2 MiB
    const size_t SZ_WKT = (size_t)DKV * Dd * 2;      // 0.5 MiB
    const size_t SZ_QB = (size_t)ROWS * Dd * 2;      // 8 MiB
    const size_t SZ_KS = (size_t)ROWS * DKV * 2;     // 2 MiB

    size_t off = 0;
    u16* xc = (u16*)(ws + off);
    u16* krope = (u16*)(ws + off); off += SZ_XC;        // alias
    u32* kp = (u32*)(ws + off); off += (SZ_KP + 255) & ~(size_t)255;
    u16* wqT = (u16*)(ws + off);
    u16* vtb = (u16*)(ws + off); off += SZ_WQT;         // alias (both 2 MiB)
    u16* wkT = (u16*)(ws + off); off += SZ_WKT;
    u16* wvT = (u16*)(ws + off); off += SZ_WKT;
    u16* qbuf = (u16*)(ws + off); off += SZ_QB;
    u16* ksmall = (u16*)(ws + off); off += SZ_KS;
    u16* vsmall = (u16*)(ws + off); off += SZ_KS;
    (void)ws_size; (void)in_sizes; (void)n_in; (void)out_size;

    prep_kernel<<<ROWS, 256, 0, stream>>>(x, xc, kp);
    transpose_kernel<<<dim3(Dd / 32, Dd / 32), 256, 0, stream>>>(Wq, wqT, Dd, Dd);
    transpose_kernel<<<dim3(DKV / 32, Dd / 32), 256, 0, stream>>>(Wk, wkT, Dd, DKV);
    transpose_kernel<<<dim3(DKV / 32, Dd / 32), 256, 0, stream>>>(Wv, wvT, Dd, DKV);

    gemm_tn_kernel<<<dim3(Dd / 128, ROWS / 128), 256, 0, stream>>>(xc, wqT, qbuf, ROWS, Dd, Dd);
    gemm_tn_kernel<<<dim3(DKV / 128, ROWS / 128), 256, 0, stream>>>(xc, wkT, ksmall, ROWS, DKV, Dd);
    gemm_tn_kernel<<<dim3(DKV / 128, ROWS / 128), 256, 0, stream>>>(xc, wvT, vsmall, ROWS, DKV, Dd);

    rope_q_kernel<<<ROWS, 256, 0, stream>>>(qbuf);
    rope_k_kernel<<<ROWS, 256, 0, stream>>>(ksmall, krope);   // krope overlays dead xc
    vtrans_kernel<<<dim3(DKV / 32, Ss / 32, Bb), 256, 0, stream>>>(vsmall, vtb); // vtb overlays dead wqT

    attn_kernel<<<dim3(Ss / 64, Hh, Bb), 256, 0, stream>>>(qbuf, krope, vtb, kp, out);
}

// Round 3
// 198.215 us; speedup vs baseline: 1.6405x; 1.6405x over previous
//
#include <hip/hip_runtime.h>
#include <hip/hip_bf16.h>
#include <math.h>

typedef unsigned short u16;
typedef unsigned int u32;
typedef __bf16 bf16x8 __attribute__((ext_vector_type(8)));
typedef float fx4 __attribute__((ext_vector_type(4)));

#define MFMA16(a, b, c) __builtin_amdgcn_mfma_f32_16x16x32_bf16(a, b, c, 0, 0, 0)

static constexpr int Bb = 2, Ss = 2048, Dd = 1024, Hh = 16, DKV = 256;
static constexpr int NQKV = 1536; // 1024 q | 256 k | 256 v
static constexpr int ROWS = Bb * Ss; // 4096

__device__ __forceinline__ u16 f2bf(float f) {
    union { float f; u32 i; } v; v.f = f;
    u32 u = v.i;
    return (u16)((u + 0x7FFFu + ((u >> 16) & 1u)) >> 16);
}

// async global->LDS, 16B per lane; LDS dest is wave-uniform base + lane*16
__device__ __forceinline__ void gl16(const u16* g, u16* l) {
    __builtin_amdgcn_global_load_lds(
        (const __attribute__((address_space(1))) void*)g,
        (__attribute__((address_space(3))) void*)l, 16, 0, 0);
}

template <int CTRL>
__device__ __forceinline__ float dppf(float x) {
    return __int_as_float(
        __builtin_amdgcn_mov_dpp(__float_as_int(x), CTRL, 0xF, 0xF, true));
}
// reduction across a 16-lane DPP row (our q-row groups are lanes [16*quad, 16*quad+15])
__device__ __forceinline__ float rmax16(float x) {
    x = fmaxf(x, dppf<0xB1>(x));   // quad_perm [1,0,3,2]
    x = fmaxf(x, dppf<0x4E>(x));   // quad_perm [2,3,0,1]
    x = fmaxf(x, dppf<0x124>(x));  // row_ror:4
    x = fmaxf(x, dppf<0x128>(x));  // row_ror:8
    return x;
}
__device__ __forceinline__ float rsum16(float x) {
    x += dppf<0xB1>(x);
    x += dppf<0x4E>(x);
    x += dppf<0x124>(x);
    x += dppf<0x128>(x);
    return x;
}

// ---------------- prep: f32 x -> bf16 xc (NaN->0), pad bitmask ----------------
__global__ void prep_kernel(const float* __restrict__ x, u16* __restrict__ xc,
                            u32* __restrict__ kpb) {
    int row = blockIdx.x;
    int t = threadIdx.x;
    __shared__ int flag;
    if (t == 0) flag = 0;
    __syncthreads();
    float4 d = *(const float4*)(x + (size_t)row * Dd + t * 4);
    int any = 0;
    float a0 = d.x, a1 = d.y, a2 = d.z, a3 = d.w;
    if ((__float_as_uint(a0) & 0x7FFFFFFFu) > 0x7F800000u) { a0 = 0.f; any = 1; }
    if ((__float_as_uint(a1) & 0x7FFFFFFFu) > 0x7F800000u) { a1 = 0.f; any = 1; }
    if ((__float_as_uint(a2) & 0x7FFFFFFFu) > 0x7F800000u) { a2 = 0.f; any = 1; }
    if ((__float_as_uint(a3) & 0x7FFFFFFFu) > 0x7F800000u) { a3 = 0.f; any = 1; }
    if (any) atomicOr(&flag, 1);
    uint2 o;
    o.x = (u32)f2bf(a0) | ((u32)f2bf(a1) << 16);
    o.y = (u32)f2bf(a2) | ((u32)f2bf(a3) << 16);
    *(uint2*)(xc + (size_t)row * Dd + t * 4) = o;
    __syncthreads();
    if (t == 0 && flag) {
        int b = row >> 11, s = row & (Ss - 1);
        atomicOr(&kpb[b * 64 + (s >> 5)], 1u << (s & 31));
    }
}

// ------------- transpose f32 (R x C) -> bf16 (C x R) -------------
__global__ void transpose_kernel(const float* __restrict__ in, u16* __restrict__ out,
                                 int R, int C) {
    __shared__ u16 tile[32][33];
    int c0 = blockIdx.x * 32, r0 = blockIdx.y * 32;
    int tx = threadIdx.x & 31, ty = threadIdx.x >> 5;
    for (int i = 0; i < 32; i += 8)
        tile[ty + i][tx] = f2bf(in[(size_t)(r0 + ty + i) * C + c0 + tx]);
    __syncthreads();
    for (int i = 0; i < 32; i += 8)
        out[(size_t)(c0 + ty + i) * R + r0 + tx] = tile[tx][ty + i];
}

// ---------------- fused QKV GEMM: qkv[4096,1536] = xc[4096,1024] * wAll[1536,1024]^T
__global__ __launch_bounds__(256) void gemm_qkv(
    const u16* __restrict__ A, const u16* __restrict__ Bt, u16* __restrict__ C) {
    __shared__ __align__(16) u16 As[2][128 * 32];
    __shared__ __align__(16) u16 Bs[2][128 * 32];
    int t = threadIdx.x, w = t >> 6, lane = t & 63;
    int l15 = lane & 15, quad = lane >> 4;
    int col0 = blockIdx.x * 128, row0 = blockIdx.y * 128;
    int wm = w >> 1, wn = w & 1;
    fx4 acc[4][4];
#pragma unroll
    for (int i = 0; i < 4; ++i)
#pragma unroll
        for (int j = 0; j < 4; ++j) acc[i][j] = (fx4){0.f, 0.f, 0.f, 0.f};

    auto stage = [&](int kb, int buf) {
#pragma unroll
        for (int i = 0; i < 2; ++i) {
            int slot = i * 256 + t;
            int row = slot >> 2, p = slot & 3, g = p ^ ((row >> 1) & 3);
            // wave-uniform LDS base: slots [i*256 + w*64, +64)
            gl16(A + (size_t)(row0 + row) * Dd + kb * 32 + g * 8,
                 &As[buf][(i * 256 + w * 64) * 8]);
            gl16(Bt + (size_t)(col0 + row) * Dd + kb * 32 + g * 8,
                 &Bs[buf][(i * 256 + w * 64) * 8]);
        }
    };

    stage(0, 0);
    int buf = 0;
    for (int kb = 0; kb < 32; ++kb) {
        __syncthreads(); // drains prefetch vmcnt + prior reads
        if (kb + 1 < 32) stage(kb + 1, buf ^ 1);
        bf16x8 af[4], bfr[4];
#pragma unroll
        for (int mi = 0; mi < 4; ++mi) {
            int row = wm * 64 + mi * 16 + l15;
            af[mi] = *(const bf16x8*)(&As[buf][row * 32 + ((quad ^ ((row >> 1) & 3)) * 8)]);
        }
#pragma unroll
        for (int ni = 0; ni < 4; ++ni) {
            int row = wn * 64 + ni * 16 + l15;
            bfr[ni] = *(const bf16x8*)(&Bs[buf][row * 32 + ((quad ^ ((row >> 1) & 3)) * 8)]);
        }
#pragma unroll
        for (int mi = 0; mi < 4; ++mi)
#pragma unroll
            for (int ni = 0; ni < 4; ++ni)
                acc[mi][ni] = MFMA16(af[mi], bfr[ni], acc[mi][ni]);
        buf ^= 1;
    }
#pragma unroll
    for (int mi = 0; mi < 4; ++mi) {
        int rbase = row0 + wm * 64 + mi * 16 + quad * 4;
#pragma unroll
        for (int ni = 0; ni < 4; ++ni) {
            int ccol = col0 + wn * 64 + ni * 16 + l15;
#pragma unroll
            for (int r = 0; r < 4; ++r)
                C[(size_t)(rbase + r) * NQKV + ccol] = f2bf(acc[mi][ni][r]);
        }
    }
}

// ---------------- RoPE ----------------
static constexpr float L2T_OVER = 0.0259525632f; // log2(10000)/512

__global__ void rope_q_kernel(u16* __restrict__ qkv) {
    int row = blockIdx.x, t = threadIdx.x;
    float pos = (float)(row & (Ss - 1));
    u16* p = qkv + (size_t)row * NQKV + t * 4;
    uint2 d = *(const uint2*)p;
    float x0 = __uint_as_float(((u32)(d.x & 0xFFFF)) << 16);
    float x1 = __uint_as_float((d.x >> 16) << 16);
    float x2 = __uint_as_float(((u32)(d.y & 0xFFFF)) << 16);
    float x3 = __uint_as_float((d.y >> 16) << 16);
    float j0 = (float)(2 * t), j1 = j0 + 1.0f;
    float f0 = exp2f(-j0 * L2T_OVER), f1 = exp2f(-j1 * L2T_OVER);
    float s0, c0, s1, c1;
    sincosf(pos * f0, &s0, &c0);
    sincosf(pos * f1, &s1, &c1);
    float r0 = x0 * c0 - x1 * s0, r1 = x0 * s0 + x1 * c0;
    float r2 = x2 * c1 - x3 * s1, r3 = x2 * s1 + x3 * c1;
    uint2 o;
    o.x = (u32)f2bf(r0) | ((u32)f2bf(r1) << 16);
    o.y = (u32)f2bf(r2) | ((u32)f2bf(r3) << 16);
    *(uint2*)p = o;
}

// k cols of qkv (rows x 256 @offset 1024) -> k_rope (rows x 1024)
__global__ void rope_k_kernel(const u16* __restrict__ qkv, u16* __restrict__ kr) {
    int row = blockIdx.x, t = threadIdx.x;
    float pos = (float)(row & (Ss - 1));
    float kv = __uint_as_float(((u32)qkv[(size_t)row * NQKV + Dd + t]) << 16);
    float j0 = (float)(2 * t), j1 = j0 + 1.0f;
    float f0 = exp2f(-j0 * L2T_OVER), f1 = exp2f(-j1 * L2T_OVER);
    float s0, c0, s1, c1;
    sincosf(pos * f0, &s0, &c0);
    sincosf(pos * f1, &s1, &c1);
    float r0 = kv * (c0 - s0), r1 = kv * (s0 + c0);
    float r2 = kv * (c1 - s1), r3 = kv * (s1 + c1);
    uint2 o;
    o.x = (u32)f2bf(r0) | ((u32)f2bf(r1) << 16);
    o.y = (u32)f2bf(r2) | ((u32)f2bf(r3) << 16);
    *(uint2*)(kr + (size_t)row * Dd + t * 4) = o;
}

// v cols of qkv (per b: S x 256 @offset 1280) -> v_t (per b: 256 x S)
__global__ void vtrans_kernel(const u16* __restrict__ qkv, u16* __restrict__ out) {
    __shared__ u16 tile[32][33];
    int b = blockIdx.z;
    int c0 = blockIdx.x * 32, r0 = blockIdx.y * 32;
    int tx = threadIdx.x & 31, ty = threadIdx.x >> 5;
    for (int i = 0; i < 32; i += 8)
        tile[ty + i][tx] =
            qkv[(size_t)(b * Ss + r0 + ty + i) * NQKV + 1280 + c0 + tx];
    __syncthreads();
    for (int i = 0; i < 32; i += 8)
        out[(size_t)(b * DKV + c0 + ty + i) * Ss + r0 + tx] = tile[tx][ty + i];
}

// ---------------- flash attention ----------------
// flat grid 512: b=bid>>8, h=(bid>>4)&15, tile paired LPT; block=256 (4 waves x 32q)
__global__ __launch_bounds__(256) void attn_kernel(
    const u16* __restrict__ qkv, const u16* __restrict__ kr,
    const u16* __restrict__ vt, const u32* __restrict__ kpb,
    float* __restrict__ out) {
    __shared__ __align__(16) u16 Ks[2][64 * 64];  // 64 keys x 64 dims, chunk-swizzled
    __shared__ __align__(16) u16 Vs[2][16 * 64];  // 16 feats x 64 keys, chunk-swizzled
    __shared__ __align__(16) u16 Ps[4][32 * 72];  // per-wave P, padded stride 72

    int t = threadIdx.x, w = t >> 6, lane = t & 63;
    int l15 = lane & 15, quad = lane >> 4;
    int bid = blockIdx.x;
    int b = bid >> 8, h = (bid >> 4) & 15, ts = bid & 15;
    int tile = b ? (15 - ts) : ts; // pair long+short on each CU
    int q0 = tile * 128;
    int nkb = 2 * tile + 2;

    // Q fragments: A[m=q(l15)][k=dim(quad*8+j)]
    const u16* qA = qkv + (size_t)(b * Ss + q0 + w * 32 + l15) * NQKV + h * 64;
    const u16* qB = qA + (size_t)16 * NQKV;
    bf16x8 qfA0 = *(const bf16x8*)(qA + quad * 8);
    bf16x8 qfA1 = *(const bf16x8*)(qA + 32 + quad * 8);
    bf16x8 qfB0 = *(const bf16x8*)(qB + quad * 8);
    bf16x8 qfB1 = *(const bf16x8*)(qB + 32 + quad * 8);

    auto stageK = [&](int k0, int buf) {
#pragma unroll
        for (int i = 0; i < 2; ++i) {
            int row = i * 32 + w * 8 + (lane >> 3);
            int p = lane & 7, g = p ^ (row & 7);
            gl16(kr + (size_t)(b * Ss + k0 + row) * Dd + h * 64 + g * 8,
                 &Ks[buf][(i * 32 + w * 8) * 64]);
        }
    };
    auto stageV = [&](int k0, int buf) {
        if (w < 2) {
            int row = w * 8 + (lane >> 3);
            int p = lane & 7, g = p ^ (row & 7);
            gl16(vt + (size_t)(b * DKV + h * 16 + row) * Ss + k0 + g * 8,
                 &Vs[buf][(w * 8) * 64]);
        }
    };

    float mA[4], lA[4], mB[4], lB[4];
    fx4 oA = (fx4){0.f, 0.f, 0.f, 0.f}, oB = (fx4){0.f, 0.f, 0.f, 0.f};
#pragma unroll
    for (int r = 0; r < 4; ++r) { mA[r] = mB[r] = -1e30f; lA[r] = lB[r] = 0.f; }

    stageK(0, 0);
    stageV(0, 0);
    int buf = 0;
    const int qAb = q0 + w * 32 + quad * 4; // q-half A row base for this lane
    for (int kb = 0; kb < nkb; ++kb) {
        int k0 = kb * 64;
        __syncthreads(); // drains prefetch vmcnt; prior-iter LDS reads done
        if (kb + 1 < nkb) { stageK(k0 + 64, buf ^ 1); stageV(k0 + 64, buf ^ 1); }
        u32 pw0 = kpb[b * 64 + (k0 >> 5)];
        u32 pw1 = kpb[b * 64 + (k0 >> 5) + 1];

        // scores: C[row=q(quad*4+r)][col=key(l15)] per 16-key tile
        fx4 sA[4], sB[4];
#pragma unroll
        for (int tt = 0; tt < 4; ++tt) {
            const u16* kbase = &Ks[buf][(tt * 16 + l15) * 64];
            bf16x8 kf0 = *(const bf16x8*)(kbase + ((quad ^ (l15 & 7)) * 8));
            bf16x8 kf1 = *(const bf16x8*)(kbase + (((quad + 4) ^ (l15 & 7)) * 8));
            fx4 z = (fx4){0.f, 0.f, 0.f, 0.f};
            fx4 a = MFMA16(qfA0, kf0, z);
            a = MFMA16(qfA1, kf1, a);
            sA[tt] = a;
            fx4 c = MFMA16(qfB0, kf0, z);
            c = MFMA16(qfB1, kf1, c);
            sB[tt] = c;
        }

        u32 padbit[4];
#pragma unroll
        for (int tt = 0; tt < 4; ++tt)
            padbit[tt] = ((tt & 2 ? pw1 : pw0) >> ((tt * 16 + l15) & 31)) & 1u;

        float alA[4], alB[4];
#pragma unroll
        for (int r = 0; r < 4; ++r) {
            int qq = qAb + r;
            float v0_ = (k0 + 0 * 16 + l15 <= qq && !padbit[0]) ? sA[0][r] * 0.125f : -1e9f;
            float v1_ = (k0 + 1 * 16 + l15 <= qq && !padbit[1]) ? sA[1][r] * 0.125f : -1e9f;
            float v2_ = (k0 + 2 * 16 + l15 <= qq && !padbit[2]) ? sA[2][r] * 0.125f : -1e9f;
            float v3_ = (k0 + 3 * 16 + l15 <= qq && !padbit[3]) ? sA[3][r] * 0.125f : -1e9f;
            float mx = rmax16(fmaxf(fmaxf(v0_, v1_), fmaxf(v2_, v3_)));
            float mn = fmaxf(mA[r], mx);
            float al = __expf(mA[r] - mn);
            mA[r] = mn;
            float e0 = __expf(v0_ - mn), e1 = __expf(v1_ - mn);
            float e2 = __expf(v2_ - mn), e3 = __expf(v3_ - mn);
            lA[r] = lA[r] * al + rsum16((e0 + e1) + (e2 + e3));
            alA[r] = al;
            int prow = (quad * 4 + r) * 72 + l15;
            Ps[w][prow + 0] = f2bf(e0);
            Ps[w][prow + 16] = f2bf(e1);
            Ps[w][prow + 32] = f2bf(e2);
            Ps[w][prow + 48] = f2bf(e3);
        }
#pragma unroll
        for (int r = 0; r < 4; ++r) {
            int qq = qAb + 16 + r;
            float v0_ = (k0 + 0 * 16 + l15 <= qq && !padbit[0]) ? sB[0][r] * 0.125f : -1e9f;
            float v1_ = (k0 + 1 * 16 + l15 <= qq && !padbit[1]) ? sB[1][r] * 0.125f : -1e9f;
            float v2_ = (k0 + 2 * 16 + l15 <= qq && !padbit[2]) ? sB[2][r] * 0.125f : -1e9f;
            float v3_ = (k0 + 3 * 16 + l15 <= qq && !padbit[3]) ? sB[3][r] * 0.125f : -1e9f;
            float mx = rmax16(fmaxf(fmaxf(v0_, v1_), fmaxf(v2_, v3_)));
            float mn = fmaxf(mB[r], mx);
            float al = __expf(mB[r] - mn);
            mB[r] = mn;
            float e0 = __expf(v0_ - mn), e1 = __expf(v1_ - mn);
            float e2 = __expf(v2_ - mn), e3 = __expf(v3_ - mn);
            lB[r] = lB[r] * al + rsum16((e0 + e1) + (e2 + e3));
            alB[r] = al;
            int prow = (16 + quad * 4 + r) * 72 + l15;
            Ps[w][prow + 0] = f2bf(e0);
            Ps[w][prow + 16] = f2bf(e1);
            Ps[w][prow + 32] = f2bf(e2);
            Ps[w][prow + 48] = f2bf(e3);
        }
#pragma unroll
        for (int r = 0; r < 4; ++r) { oA[r] *= alA[r]; oB[r] *= alB[r]; }

        // PV: A=P[m=q(l15)][k=key], B=V[n=feat(l15)][k=key]; same-wave P, no barrier
        const u16* PsA = Ps[w];
        const u16* PsB = Ps[w] + 16 * 72;
#pragma unroll
        for (int hh = 0; hh < 2; ++hh) {
            bf16x8 vf = *(const bf16x8*)(&Vs[buf][l15 * 64 + (((quad + 4 * hh) ^ (l15 & 7)) * 8)]);
            bf16x8 pa = *(const bf16x8*)(PsA + l15 * 72 + hh * 32 + quad * 8);
            bf16x8 pb = *(const bf16x8*)(PsB + l15 * 72 + hh * 32 + quad * 8);
            oA = MFMA16(pa, vf, oA);
            oB = MFMA16(pb, vf, oB);
        }
        buf ^= 1;
    }

    // epilogue: out[b,q,h*64+4u..+3] = O_small[u] replicated x4 (f32)
#pragma unroll
    for (int r = 0; r < 4; ++r) {
        float a = oA[r] / lA[r];
        float4 o4 = {a, a, a, a};
        *(float4*)(out + (size_t)(b * Ss + qAb + r) * Dd + h * 64 + l15 * 4) = o4;
        float bb = oB[r] / lB[r];
        float4 o5 = {bb, bb, bb, bb};
        *(float4*)(out + (size_t)(b * Ss + qAb + 16 + r) * Dd + h * 64 + l15 * 4) = o5;
    }
}

// ---------------- launch ----------------
extern "C" void kernel_launch(void* const* d_in, const int* in_sizes, int n_in,
                              void* d_out, int out_size, void* d_ws, size_t ws_size,
                              hipStream_t stream) {
    const float* x = (const float*)d_in[0];
    const float* Wq = (const float*)d_in[1];
    const float* Wk = (const float*)d_in[2];
    const float* Wv = (const float*)d_in[3];
    float* out = (float*)d_out;

    char* ws = (char*)d_ws;
    const size_t SZ_XC = (size_t)ROWS * Dd * 2;       // 8 MiB (aliased by krope)
    const size_t SZ_KPB = 4096;
    const size_t SZ_WALL = (size_t)NQKV * Dd * 2;     // 3 MiB (aliased by vtb, 2 MiB)
    const size_t SZ_QKV = (size_t)ROWS * NQKV * 2;    // 12 MiB

    size_t off = 0;
    u16* xc = (u16*)(ws + off);
    u16* krope = (u16*)(ws + off); off += SZ_XC;      // alias: xc dead after gemm
    u32* kpb = (u32*)(ws + off); off += SZ_KPB;
    u16* wAll = (u16*)(ws + off);
    u16* vtb = (u16*)(ws + off); off += SZ_WALL;      // alias: wAll dead after gemm
    u16* qkv = (u16*)(ws + off); off += SZ_QKV;
    (void)ws_size; (void)in_sizes; (void)n_in; (void)out_size;

    hipMemsetAsync(kpb, 0, 2 * 64 * 4, stream);
    prep_kernel<<<ROWS, 256, 0, stream>>>(x, xc, kpb);
    transpose_kernel<<<dim3(32, 32), 256, 0, stream>>>(Wq, wAll, Dd, Dd);
    transpose_kernel<<<dim3(8, 32), 256, 0, stream>>>(Wk, wAll + (size_t)Dd * Dd, Dd, DKV);
    transpose_kernel<<<dim3(8, 32), 256, 0, stream>>>(Wv, wAll + (size_t)1280 * Dd, Dd, DKV);

    gemm_qkv<<<dim3(NQKV / 128, ROWS / 128), 256, 0, stream>>>(xc, wAll, qkv);

    rope_q_kernel<<<ROWS, 256, 0, stream>>>(qkv);
    rope_k_kernel<<<ROWS, 256, 0, stream>>>(qkv, krope);
    vtrans_kernel<<<dim3(8, 64, 2), 256, 0, stream>>>(qkv, vtb);

    attn_kernel<<<512, 256, 0, stream>>>(qkv, krope, vtb, kpb, out);
}

// Round 4
// 167.217 us; speedup vs baseline: 1.9446x; 1.1854x over previous
//
#include <hip/hip_runtime.h>
#include <hip/hip_bf16.h>
#include <math.h>

typedef unsigned short u16;
typedef unsigned int u32;
typedef __bf16 bf16x8 __attribute__((ext_vector_type(8)));
typedef float fx4 __attribute__((ext_vector_type(4)));

#define MFMA16(a, b, c) __builtin_amdgcn_mfma_f32_16x16x32_bf16(a, b, c, 0, 0, 0)

static constexpr int Bb = 2, Ss = 2048, Dd = 1024, Hh = 16, DKV = 256;
static constexpr int NQKV = 1536; // 1024 q | 256 k | 256 v
static constexpr int ROWS = Bb * Ss; // 4096
static constexpr float L2T_OVER = 0.0259525632f;  // log2(10000)/512
static constexpr float SC2 = 0.18033688f;         // 0.125 * log2(e)

__device__ __forceinline__ u16 f2bf(float f) {   // RNE
    union { float f; u32 i; } v; v.f = f;
    u32 u = v.i;
    return (u16)((u + 0x7FFFu + ((u >> 16) & 1u)) >> 16);
}
__device__ __forceinline__ u16 bfr(float f) {    // RN (cheap), for P tiles
    return (u16)((__float_as_uint(f) + 0x8000u) >> 16);
}

// async global->LDS, 16B/lane; LDS dest wave-uniform base + lane*16
__device__ __forceinline__ void gl16(const u16* g, u16* l) {
    __builtin_amdgcn_global_load_lds(
        (const __attribute__((address_space(1))) void*)g,
        (__attribute__((address_space(3))) void*)l, 16, 0, 0);
}

template <int CTRL>
__device__ __forceinline__ float dppf(float x) {
    return __int_as_float(
        __builtin_amdgcn_mov_dpp(__float_as_int(x), CTRL, 0xF, 0xF, true));
}
__device__ __forceinline__ float rmax16(float x) {
    x = fmaxf(x, dppf<0xB1>(x));   // quad_perm [1,0,3,2]
    x = fmaxf(x, dppf<0x4E>(x));   // quad_perm [2,3,0,1]
    x = fmaxf(x, dppf<0x124>(x));  // row_ror:4
    x = fmaxf(x, dppf<0x128>(x));  // row_ror:8
    return x;
}
__device__ __forceinline__ float rsum16(float x) {
    x += dppf<0xB1>(x);
    x += dppf<0x4E>(x);
    x += dppf<0x124>(x);
    x += dppf<0x128>(x);
    return x;
}

// ---------- merged pre: prep(x->xc bf16, pad bits) + 3 weight transposes ----------
__global__ void pre_kernel(const float* __restrict__ x, const float* __restrict__ Wq,
                           const float* __restrict__ Wk, const float* __restrict__ Wv,
                           u16* __restrict__ xc, u32* __restrict__ kpb,
                           u16* __restrict__ wAll) {
    __shared__ u16 tile[32][33];
    __shared__ int flag;
    int bid = blockIdx.x, t = threadIdx.x;
    if (bid < 4096) {
        int row = bid;
        if (t == 0) flag = 0;
        __syncthreads();
        float4 d = *(const float4*)(x + (size_t)row * Dd + t * 4);
        int any = 0;
        float a0 = d.x, a1 = d.y, a2 = d.z, a3 = d.w;
        if ((__float_as_uint(a0) & 0x7FFFFFFFu) > 0x7F800000u) { a0 = 0.f; any = 1; }
        if ((__float_as_uint(a1) & 0x7FFFFFFFu) > 0x7F800000u) { a1 = 0.f; any = 1; }
        if ((__float_as_uint(a2) & 0x7FFFFFFFu) > 0x7F800000u) { a2 = 0.f; any = 1; }
        if ((__float_as_uint(a3) & 0x7FFFFFFFu) > 0x7F800000u) { a3 = 0.f; any = 1; }
        if (any) atomicOr(&flag, 1);
        uint2 o;
        o.x = (u32)f2bf(a0) | ((u32)f2bf(a1) << 16);
        o.y = (u32)f2bf(a2) | ((u32)f2bf(a3) << 16);
        *(uint2*)(xc + (size_t)row * Dd + t * 4) = o;
        __syncthreads();
        if (t == 0 && flag) {
            int b = row >> 11, s = row & (Ss - 1);
            atomicOr(&kpb[b * 64 + (s >> 5)], 1u << (s & 31));
        }
        return;
    }
    // transposes: f32 (R x C) -> bf16 (C x R)
    const float* in; u16* out; int C, bx, by;
    if (bid < 5120) { int i = bid - 4096; in = Wq; out = wAll; C = Dd; bx = i & 31; by = i >> 5; }
    else if (bid < 5376) { int i = bid - 5120; in = Wk; out = wAll + (size_t)Dd * Dd; C = DKV; bx = i & 7; by = i >> 3; }
    else { int i = bid - 5376; in = Wv; out = wAll + (size_t)1280 * Dd; C = DKV; bx = i & 7; by = i >> 3; }
    int c0 = bx * 32, r0 = by * 32;
    int tx = t & 31, ty = t >> 5;
    for (int i = 0; i < 32; i += 8)
        tile[ty + i][tx] = f2bf(in[(size_t)(r0 + ty + i) * C + c0 + tx]);
    __syncthreads();
    for (int i = 0; i < 32; i += 8)
        out[(size_t)(c0 + ty + i) * Dd + r0 + tx] = tile[tx][ty + i];
}

// ---------------- fused QKV GEMM: qkv[4096,1536] = xc * wAll^T ----------------
__global__ __launch_bounds__(256) void gemm_qkv(
    const u16* __restrict__ A, const u16* __restrict__ Bt, u16* __restrict__ C) {
    __shared__ __align__(16) u16 As[2][128 * 32];
    __shared__ __align__(16) u16 Bs[2][128 * 32];
    int t = threadIdx.x, w = t >> 6, lane = t & 63;
    int l15 = lane & 15, quad = lane >> 4;
    int col0 = blockIdx.x * 128, row0 = blockIdx.y * 128;
    int wm = w >> 1, wn = w & 1;
    fx4 acc[4][4];
#pragma unroll
    for (int i = 0; i < 4; ++i)
#pragma unroll
        for (int j = 0; j < 4; ++j) acc[i][j] = (fx4){0.f, 0.f, 0.f, 0.f};

    auto stage = [&](int kb, int buf) {
#pragma unroll
        for (int i = 0; i < 2; ++i) {
            int slot = i * 256 + t;
            int row = slot >> 2, p = slot & 3, g = p ^ ((row >> 1) & 3);
            gl16(A + (size_t)(row0 + row) * Dd + kb * 32 + g * 8,
                 &As[buf][(i * 256 + w * 64) * 8]);
            gl16(Bt + (size_t)(col0 + row) * Dd + kb * 32 + g * 8,
                 &Bs[buf][(i * 256 + w * 64) * 8]);
        }
    };

    stage(0, 0);
    int buf = 0;
    for (int kb = 0; kb < 32; ++kb) {
        __syncthreads();
        if (kb + 1 < 32) stage(kb + 1, buf ^ 1);
        bf16x8 af[4], bfr4[4];
#pragma unroll
        for (int mi = 0; mi < 4; ++mi) {
            int row = wm * 64 + mi * 16 + l15;
            af[mi] = *(const bf16x8*)(&As[buf][row * 32 + ((quad ^ ((row >> 1) & 3)) * 8)]);
        }
#pragma unroll
        for (int ni = 0; ni < 4; ++ni) {
            int row = wn * 64 + ni * 16 + l15;
            bfr4[ni] = *(const bf16x8*)(&Bs[buf][row * 32 + ((quad ^ ((row >> 1) & 3)) * 8)]);
        }
#pragma unroll
        for (int mi = 0; mi < 4; ++mi)
#pragma unroll
            for (int ni = 0; ni < 4; ++ni)
                acc[mi][ni] = MFMA16(af[mi], bfr4[ni], acc[mi][ni]);
        buf ^= 1;
    }
#pragma unroll
    for (int mi = 0; mi < 4; ++mi) {
        int rbase = row0 + wm * 64 + mi * 16 + quad * 4;
#pragma unroll
        for (int ni = 0; ni < 4; ++ni) {
            int ccol = col0 + wn * 64 + ni * 16 + l15;
#pragma unroll
            for (int r = 0; r < 4; ++r)
                C[(size_t)(rbase + r) * NQKV + ccol] = f2bf(acc[mi][ni][r]);
        }
    }
}

// ---------- merged post: rope_k (k cols -> krope) + vtrans (v cols -> vtb) ----------
__global__ void post_kernel(const u16* __restrict__ qkv, u16* __restrict__ kr,
                            u16* __restrict__ vtb) {
    __shared__ u16 tile[32][33];
    int bid = blockIdx.x, t = threadIdx.x;
    if (bid < 4096) {
        int row = bid;
        float pos = (float)(row & (Ss - 1));
        float kv = __uint_as_float(((u32)qkv[(size_t)row * NQKV + Dd + t]) << 16);
        float j0 = (float)(2 * t), j1 = j0 + 1.0f;
        float f0 = exp2f(-j0 * L2T_OVER), f1 = exp2f(-j1 * L2T_OVER);
        float s0, c0, s1, c1;
        sincosf(pos * f0, &s0, &c0);
        sincosf(pos * f1, &s1, &c1);
        float r0 = kv * (c0 - s0), r1 = kv * (s0 + c0);
        float r2 = kv * (c1 - s1), r3 = kv * (s1 + c1);
        uint2 o;
        o.x = (u32)f2bf(r0) | ((u32)f2bf(r1) << 16);
        o.y = (u32)f2bf(r2) | ((u32)f2bf(r3) << 16);
        *(uint2*)(kr + (size_t)row * Dd + t * 4) = o;
        return;
    }
    int i = bid - 4096;
    int b = i >> 9, by = (i & 511) >> 3, bx = i & 7;
    int c0 = bx * 32, r0 = by * 32;
    int tx = t & 31, ty = t >> 5;
    for (int k = 0; k < 32; k += 8)
        tile[ty + k][tx] = qkv[(size_t)(b * Ss + r0 + ty + k) * NQKV + 1280 + c0 + tx];
    __syncthreads();
    for (int k = 0; k < 32; k += 8)
        vtb[(size_t)(b * DKV + c0 + ty + k) * Ss + r0 + tx] = tile[tx][ty + k];
}

// -------- Q fragment loader with in-register RoPE (pairs are lane-local) --------
__device__ __forceinline__ bf16x8 ropeFrag(uint4 raw, float pos, float jbase) {
    u32 W[4] = {raw.x, raw.y, raw.z, raw.w};
    union { u32 u[4]; bf16x8 v; } o;
#pragma unroll
    for (int c = 0; c < 4; ++c) {
        float x0 = __uint_as_float(W[c] << 16);
        float x1 = __uint_as_float(W[c] & 0xFFFF0000u);
        float f = exp2f(-(jbase + (float)c) * L2T_OVER);
        float sn, cs;
        sincosf(pos * f, &sn, &cs);
        float r0 = x0 * cs - x1 * sn, r1 = x0 * sn + x1 * cs;
        o.u[c] = (u32)f2bf(r0) | ((u32)f2bf(r1) << 16);
    }
    return o.v;
}

// ---------------- flash attention ----------------
// grid 1024: tile = 31 - bid/32 (descending work); hh=bid&31 -> (b,h)
// block 256 = 4 waves x 16 q; K-tile 64, double-buffered gl16 staging
__global__ __launch_bounds__(256) void attn_kernel(
    const u16* __restrict__ qkv, const u16* __restrict__ kr,
    const u16* __restrict__ vt, const u32* __restrict__ kpb,
    float* __restrict__ out) {
    __shared__ __align__(16) u16 Ks[2][64 * 64];
    __shared__ __align__(16) u16 Vs[2][16 * 64];
    __shared__ __align__(16) u16 Ps[4][16 * 72];

    int t = threadIdx.x, w = t >> 6, lane = t & 63;
    int l15 = lane & 15, quad = lane >> 4;
    int bid = blockIdx.x;
    int tile = 31 - (bid >> 5);
    int hh = bid & 31, b = hh >> 4, h = hh & 15;
    int q0 = tile * 64;
    int nkb = tile + 1;

    // Q A-frag with fused RoPE: m=l15 (q row), k=quad*8+j (dim)
    int pos = q0 + w * 16 + l15;
    const u16* qp = qkv + (size_t)(b * Ss + pos) * NQKV + h * 64;
    float jb = (float)(h * 32 + quad * 4);
    bf16x8 qf0 = ropeFrag(*(const uint4*)(qp + quad * 8), (float)pos, jb);
    bf16x8 qf1 = ropeFrag(*(const uint4*)(qp + 32 + quad * 8), (float)pos, jb + 16.f);

    auto stageK = [&](int k0, int buf) {
#pragma unroll
        for (int i = 0; i < 2; ++i) {
            int row = i * 32 + w * 8 + (lane >> 3);
            int g = (lane & 7) ^ (row & 7);
            gl16(kr + (size_t)(b * Ss + k0 + row) * Dd + h * 64 + g * 8,
                 &Ks[buf][(i * 32 + w * 8) * 64]);
        }
    };
    auto stageV = [&](int k0, int buf) {
        if (w < 2) {
            int row = w * 8 + (lane >> 3);
            int g = (lane & 7) ^ (row & 7);
            gl16(vt + (size_t)(b * DKV + h * 16 + row) * Ss + k0 + g * 8,
                 &Vs[buf][(w * 8) * 64]);
        }
    };

    float m_r[4], l_r[4];
    fx4 oacc = (fx4){0.f, 0.f, 0.f, 0.f};
#pragma unroll
    for (int r = 0; r < 4; ++r) { m_r[r] = -1e30f; l_r[r] = 0.f; }

    stageK(0, 0);
    stageV(0, 0);
    int buf = 0;
    const int qrb = q0 + w * 16 + quad * 4;  // this lane's score-row q base
    const int qmin = q0 + w * 16;

    for (int kb = 0; kb < nkb; ++kb) {
        int k0 = kb * 64;
        __syncthreads();  // drains prefetch vmcnt; prior LDS reads complete
        if (kb + 1 < nkb) { stageK(k0 + 64, buf ^ 1); stageV(k0 + 64, buf ^ 1); }

        // scores: per 16-key tile tt, C[row=quad*4+r][col=key l15]
        fx4 s[4];
#pragma unroll
        for (int tt = 0; tt < 4; ++tt) {
            const u16* kb_ = &Ks[buf][(tt * 16 + l15) * 64];
            bf16x8 kf0 = *(const bf16x8*)(kb_ + ((quad ^ (l15 & 7)) * 8));
            bf16x8 kf1 = *(const bf16x8*)(kb_ + (((quad + 4) ^ (l15 & 7)) * 8));
            fx4 z = (fx4){0.f, 0.f, 0.f, 0.f};
            fx4 a = MFMA16(qf0, kf0, z);
            s[tt] = MFMA16(qf1, kf1, a);
        }

        u32 pw0 = kpb[b * 64 + (k0 >> 5)];
        u32 pw1 = kpb[b * 64 + (k0 >> 5) + 1];
        bool fast = (k0 + 63 <= qmin) & ((pw0 | pw1) == 0u);

        float v[4][4];
        if (fast) {
#pragma unroll
            for (int tt = 0; tt < 4; ++tt)
#pragma unroll
                for (int r = 0; r < 4; ++r) v[tt][r] = s[tt][r] * SC2;
        } else {
            u32 padb[4];
#pragma unroll
            for (int tt = 0; tt < 4; ++tt)
                padb[tt] = ((tt & 2 ? pw1 : pw0) >> ((tt * 16 + l15) & 31)) & 1u;
#pragma unroll
            for (int r = 0; r < 4; ++r) {
                int qq = qrb + r;
#pragma unroll
                for (int tt = 0; tt < 4; ++tt)
                    v[tt][r] = (k0 + tt * 16 + l15 <= qq && !padb[tt])
                                   ? s[tt][r] * SC2 : -3e8f;
            }
        }

#pragma unroll
        for (int r = 0; r < 4; ++r) {
            float mx = rmax16(fmaxf(fmaxf(v[0][r], v[1][r]), fmaxf(v[2][r], v[3][r])));
            float mn = fmaxf(m_r[r], mx);
            float al = exp2f(m_r[r] - mn);
            m_r[r] = mn;
            float e0 = exp2f(v[0][r] - mn), e1 = exp2f(v[1][r] - mn);
            float e2 = exp2f(v[2][r] - mn), e3 = exp2f(v[3][r] - mn);
            l_r[r] = l_r[r] * al + rsum16((e0 + e1) + (e2 + e3));
            oacc[r] *= al;
            int prow = (quad * 4 + r) * 72 + l15;
            Ps[w][prow + 0] = bfr(e0);
            Ps[w][prow + 16] = bfr(e1);
            Ps[w][prow + 32] = bfr(e2);
            Ps[w][prow + 48] = bfr(e3);
        }

        // PV: A=P[m=q l15][k=key], B=V[n=feat l15][k=key]; same-wave LDS, no barrier
#pragma unroll
        for (int hh2 = 0; hh2 < 2; ++hh2) {
            bf16x8 vf = *(const bf16x8*)(&Vs[buf][l15 * 64 + (((quad + 4 * hh2) ^ (l15 & 7)) * 8)]);
            bf16x8 pf = *(const bf16x8*)(&Ps[w][l15 * 72 + hh2 * 32 + quad * 8]);
            oacc = MFMA16(pf, vf, oacc);
        }
        buf ^= 1;
    }

    // epilogue: out[b,q,h*64+4u..+3] = O_small[u] replicated x4 (f32)
#pragma unroll
    for (int r = 0; r < 4; ++r) {
        float a = oacc[r] / l_r[r];
        float4 o4 = {a, a, a, a};
        *(float4*)(out + (size_t)(b * Ss + qrb + r) * Dd + h * 64 + l15 * 4) = o4;
    }
}

// ---------------- launch ----------------
extern "C" void kernel_launch(void* const* d_in, const int* in_sizes, int n_in,
                              void* d_out, int out_size, void* d_ws, size_t ws_size,
                              hipStream_t stream) {
    const float* x = (const float*)d_in[0];
    const float* Wq = (const float*)d_in[1];
    const float* Wk = (const float*)d_in[2];
    const float* Wv = (const float*)d_in[3];
    float* out = (float*)d_out;

    char* ws = (char*)d_ws;
    const size_t SZ_XC = (size_t)ROWS * Dd * 2;    // 8 MiB (aliased by krope)
    const size_t SZ_KPB = 4096;
    const size_t SZ_WALL = (size_t)NQKV * Dd * 2;  // 3 MiB (aliased by vtb 2 MiB)
    const size_t SZ_QKV = (size_t)ROWS * NQKV * 2; // 12 MiB

    size_t off = 0;
    u16* xc = (u16*)(ws + off);
    u16* krope = (u16*)(ws + off); off += SZ_XC;   // alias: xc dead after gemm
    u32* kpb = (u32*)(ws + off); off += SZ_KPB;
    u16* wAll = (u16*)(ws + off);
    u16* vtb = (u16*)(ws + off); off += SZ_WALL;   // alias: wAll dead after gemm
    u16* qkv = (u16*)(ws + off); off += SZ_QKV;
    (void)ws_size; (void)in_sizes; (void)n_in; (void)out_size;

    hipMemsetAsync(kpb, 0, 2 * 64 * 4, stream);
    pre_kernel<<<5632, 256, 0, stream>>>(x, Wq, Wk, Wv, xc, kpb, wAll);
    gemm_qkv<<<dim3(NQKV / 128, ROWS / 128), 256, 0, stream>>>(xc, wAll, qkv);
    post_kernel<<<5120, 256, 0, stream>>>(qkv, krope, vtb);
    attn_kernel<<<1024, 256, 0, stream>>>(qkv, krope, vtb, kpb, out);
}

// Round 5
// 155.367 us; speedup vs baseline: 2.0929x; 1.0763x over previous
//
#include <hip/hip_runtime.h>
#include <hip/hip_bf16.h>
#include <math.h>

typedef unsigned short u16;
typedef unsigned int u32;
typedef __bf16 bf16x8 __attribute__((ext_vector_type(8)));
typedef float fx4 __attribute__((ext_vector_type(4)));

#define MFMA16(a, b, c) __builtin_amdgcn_mfma_f32_16x16x32_bf16(a, b, c, 0, 0, 0)

static constexpr int Bb = 2, Ss = 2048, Dd = 1024, Hh = 16, DKV = 256;
static constexpr int NQKV = 1536; // 1024 q | 256 k | 256 v
static constexpr int ROWS = Bb * Ss; // 4096
static constexpr float L2T_OVER = 0.0259525632f;  // log2(10000)/512
static constexpr float SC2 = 0.18033688f;         // 0.125 * log2(e)
static constexpr int PSTR = 76;                   // Ps row stride (bank-spread)

__device__ __forceinline__ u16 f2bf(float f) {   // RNE
    union { float f; u32 i; } v; v.f = f;
    u32 u = v.i;
    return (u16)((u + 0x7FFFu + ((u >> 16) & 1u)) >> 16);
}
__device__ __forceinline__ u16 bfr(float f) {    // RN (cheap), for P tiles
    return (u16)((__float_as_uint(f) + 0x8000u) >> 16);
}

// async global->LDS, 16B/lane; LDS dest wave-uniform base + lane*16
__device__ __forceinline__ void gl16(const u16* g, u16* l) {
    __builtin_amdgcn_global_load_lds(
        (const __attribute__((address_space(1))) void*)g,
        (__attribute__((address_space(3))) void*)l, 16, 0, 0);
}

template <int CTRL>
__device__ __forceinline__ float dppf(float x) {
    return __int_as_float(
        __builtin_amdgcn_mov_dpp(__float_as_int(x), CTRL, 0xF, 0xF, true));
}
__device__ __forceinline__ float rsum16(float x) {
    x += dppf<0xB1>(x);   // quad_perm [1,0,3,2]
    x += dppf<0x4E>(x);   // quad_perm [2,3,0,1]
    x += dppf<0x124>(x);  // row_ror:4
    x += dppf<0x128>(x);  // row_ror:8
    return x;
}

// ---------- merged pre: prep(x->xc bf16, pad bits) + 3 weight transposes ----------
__global__ void pre_kernel(const float* __restrict__ x, const float* __restrict__ Wq,
                           const float* __restrict__ Wk, const float* __restrict__ Wv,
                           u16* __restrict__ xc, u32* __restrict__ kpb,
                           u16* __restrict__ wAll) {
    __shared__ u16 tile[32][33];
    __shared__ int flag;
    int bid = blockIdx.x, t = threadIdx.x;
    if (bid < 4096) {
        int row = bid;
        if (t == 0) flag = 0;
        __syncthreads();
        float4 d = *(const float4*)(x + (size_t)row * Dd + t * 4);
        int any = 0;
        float a0 = d.x, a1 = d.y, a2 = d.z, a3 = d.w;
        if ((__float_as_uint(a0) & 0x7FFFFFFFu) > 0x7F800000u) { a0 = 0.f; any = 1; }
        if ((__float_as_uint(a1) & 0x7FFFFFFFu) > 0x7F800000u) { a1 = 0.f; any = 1; }
        if ((__float_as_uint(a2) & 0x7FFFFFFFu) > 0x7F800000u) { a2 = 0.f; any = 1; }
        if ((__float_as_uint(a3) & 0x7FFFFFFFu) > 0x7F800000u) { a3 = 0.f; any = 1; }
        if (any) atomicOr(&flag, 1);
        uint2 o;
        o.x = (u32)f2bf(a0) | ((u32)f2bf(a1) << 16);
        o.y = (u32)f2bf(a2) | ((u32)f2bf(a3) << 16);
        *(uint2*)(xc + (size_t)row * Dd + t * 4) = o;
        __syncthreads();
        if (t == 0 && flag) {
            int b = row >> 11, s = row & (Ss - 1);
            atomicOr(&kpb[b * 64 + (s >> 5)], 1u << (s & 31));
        }
        return;
    }
    // transposes: f32 (R x C) -> bf16 (C x R)
    const float* in; u16* out; int C, bx, by;
    if (bid < 5120) { int i = bid - 4096; in = Wq; out = wAll; C = Dd; bx = i & 31; by = i >> 5; }
    else if (bid < 5376) { int i = bid - 5120; in = Wk; out = wAll + (size_t)Dd * Dd; C = DKV; bx = i & 7; by = i >> 3; }
    else { int i = bid - 5376; in = Wv; out = wAll + (size_t)1280 * Dd; C = DKV; bx = i & 7; by = i >> 3; }
    int c0 = bx * 32, r0 = by * 32;
    int tx = t & 31, ty = t >> 5;
    for (int i = 0; i < 32; i += 8)
        tile[ty + i][tx] = f2bf(in[(size_t)(r0 + ty + i) * C + c0 + tx]);
    __syncthreads();
    for (int i = 0; i < 32; i += 8)
        out[(size_t)(c0 + ty + i) * Dd + r0 + tx] = tile[tx][ty + i];
}

// ---------------- fused QKV GEMM: qkv[4096,1536] = xc * wAll^T ----------------
__global__ __launch_bounds__(256) void gemm_qkv(
    const u16* __restrict__ A, const u16* __restrict__ Bt, u16* __restrict__ C) {
    __shared__ __align__(16) u16 As[2][128 * 32];
    __shared__ __align__(16) u16 Bs[2][128 * 32];
    int t = threadIdx.x, w = t >> 6, lane = t & 63;
    int l15 = lane & 15, quad = lane >> 4;
    int col0 = blockIdx.x * 128, row0 = blockIdx.y * 128;
    int wm = w >> 1, wn = w & 1;
    fx4 acc[4][4];
#pragma unroll
    for (int i = 0; i < 4; ++i)
#pragma unroll
        for (int j = 0; j < 4; ++j) acc[i][j] = (fx4){0.f, 0.f, 0.f, 0.f};

    auto stage = [&](int kb, int buf) {
#pragma unroll
        for (int i = 0; i < 2; ++i) {
            int slot = i * 256 + t;
            int row = slot >> 2, p = slot & 3, g = p ^ ((row >> 1) & 3);
            gl16(A + (size_t)(row0 + row) * Dd + kb * 32 + g * 8,
                 &As[buf][(i * 256 + w * 64) * 8]);
            gl16(Bt + (size_t)(col0 + row) * Dd + kb * 32 + g * 8,
                 &Bs[buf][(i * 256 + w * 64) * 8]);
        }
    };

    stage(0, 0);
    int buf = 0;
    for (int kb = 0; kb < 32; ++kb) {
        __syncthreads();
        if (kb + 1 < 32) stage(kb + 1, buf ^ 1);
        bf16x8 af[4], bfr4[4];
#pragma unroll
        for (int mi = 0; mi < 4; ++mi) {
            int row = wm * 64 + mi * 16 + l15;
            af[mi] = *(const bf16x8*)(&As[buf][row * 32 + ((quad ^ ((row >> 1) & 3)) * 8)]);
        }
#pragma unroll
        for (int ni = 0; ni < 4; ++ni) {
            int row = wn * 64 + ni * 16 + l15;
            bfr4[ni] = *(const bf16x8*)(&Bs[buf][row * 32 + ((quad ^ ((row >> 1) & 3)) * 8)]);
        }
#pragma unroll
        for (int mi = 0; mi < 4; ++mi)
#pragma unroll
            for (int ni = 0; ni < 4; ++ni)
                acc[mi][ni] = MFMA16(af[mi], bfr4[ni], acc[mi][ni]);
        buf ^= 1;
    }
#pragma unroll
    for (int mi = 0; mi < 4; ++mi) {
        int rbase = row0 + wm * 64 + mi * 16 + quad * 4;
#pragma unroll
        for (int ni = 0; ni < 4; ++ni) {
            int ccol = col0 + wn * 64 + ni * 16 + l15;
#pragma unroll
            for (int r = 0; r < 4; ++r)
                C[(size_t)(rbase + r) * NQKV + ccol] = f2bf(acc[mi][ni][r]);
        }
    }
}

// ---------- merged post: rope_k (k cols -> krope) + vtrans (v cols -> vtb) ----------
__global__ void post_kernel(const u16* __restrict__ qkv, u16* __restrict__ kr,
                            u16* __restrict__ vtb) {
    __shared__ u16 tile[32][33];
    int bid = blockIdx.x, t = threadIdx.x;
    if (bid < 4096) {
        int row = bid;
        float pos = (float)(row & (Ss - 1));
        float kv = __uint_as_float(((u32)qkv[(size_t)row * NQKV + Dd + t]) << 16);
        float j0 = (float)(2 * t), j1 = j0 + 1.0f;
        float f0 = exp2f(-j0 * L2T_OVER), f1 = exp2f(-j1 * L2T_OVER);
        float s0, c0, s1, c1;
        sincosf(pos * f0, &s0, &c0);
        sincosf(pos * f1, &s1, &c1);
        float r0 = kv * (c0 - s0), r1 = kv * (s0 + c0);
        float r2 = kv * (c1 - s1), r3 = kv * (s1 + c1);
        uint2 o;
        o.x = (u32)f2bf(r0) | ((u32)f2bf(r1) << 16);
        o.y = (u32)f2bf(r2) | ((u32)f2bf(r3) << 16);
        *(uint2*)(kr + (size_t)row * Dd + t * 4) = o;
        return;
    }
    int i = bid - 4096;
    int b = i >> 9, by = (i & 511) >> 3, bx = i & 7;
    int c0 = bx * 32, r0 = by * 32;
    int tx = t & 31, ty = t >> 5;
    for (int k = 0; k < 32; k += 8)
        tile[ty + k][tx] = qkv[(size_t)(b * Ss + r0 + ty + k) * NQKV + 1280 + c0 + tx];
    __syncthreads();
    for (int k = 0; k < 32; k += 8)
        vtb[(size_t)(b * DKV + c0 + ty + k) * Ss + r0 + tx] = tile[tx][ty + k];
}

// -------- Q fragment loader with in-register RoPE (pairs are lane-local) --------
__device__ __forceinline__ bf16x8 ropeFrag(uint4 raw, float pos, float jbase) {
    u32 W[4] = {raw.x, raw.y, raw.z, raw.w};
    union { u32 u[4]; bf16x8 v; } o;
#pragma unroll
    for (int c = 0; c < 4; ++c) {
        float x0 = __uint_as_float(W[c] << 16);
        float x1 = __uint_as_float(W[c] & 0xFFFF0000u);
        float f = exp2f(-(jbase + (float)c) * L2T_OVER);
        float sn, cs;
        sincosf(pos * f, &sn, &cs);
        float r0 = x0 * cs - x1 * sn, r1 = x0 * sn + x1 * cs;
        o.u[c] = (u32)f2bf(r0) | ((u32)f2bf(r1) << 16);
    }
    return o.v;
}

// ---------------- flash attention, fixed-M softmax ----------------
// grid 1024: u=bid>>5 -> balanced tile perm (per-CU sums constant, heavy first)
// block 256 = 4 waves x 16 q; K-tile 64, double-buffered gl16 staging
__global__ __launch_bounds__(256) void attn_kernel(
    const u16* __restrict__ qkv, const u16* __restrict__ kr,
    const u16* __restrict__ vt, const u32* __restrict__ kpb,
    float* __restrict__ out) {
    __shared__ __align__(16) u16 Ks[2][64 * 64];
    __shared__ __align__(16) u16 Vs[2][16 * 64];
    __shared__ __align__(16) u16 Ps[4][16 * PSTR];

    int t = threadIdx.x, w = t >> 6, lane = t & 63;
    int l15 = lane & 15, quad = lane >> 4;
    int bid = blockIdx.x;
    int u = bid >> 5, g = u >> 3, i = u & 7;
    // balanced LPT perm: g0:31-i g1:16+i g2:15-i g3:i  (col sum of iters = 66)
    int tile = (g == 0) ? (31 - i) : (g == 1) ? (16 + i) : (g == 2) ? (15 - i) : i;
    int hh = bid & 31, b = hh >> 4, h = hh & 15;
    int q0 = tile * 64;
    int nkb = tile + 1;

    // Q A-frag with fused RoPE: m=l15 (q row), k=quad*8+j (dim)
    int pos = q0 + w * 16 + l15;
    const u16* qp = qkv + (size_t)(b * Ss + pos) * NQKV + h * 64;
    float jb = (float)(h * 32 + quad * 4);
    bf16x8 qf0 = ropeFrag(*(const uint4*)(qp + quad * 8), (float)pos, jb);
    bf16x8 qf1 = ropeFrag(*(const uint4*)(qp + 32 + quad * 8), (float)pos, jb + 16.f);

    auto stageK = [&](int k0, int buf) {
#pragma unroll
        for (int i2 = 0; i2 < 2; ++i2) {
            int row = i2 * 32 + w * 8 + (lane >> 3);
            int gg = (lane & 7) ^ (row & 7);
            gl16(kr + (size_t)(b * Ss + k0 + row) * Dd + h * 64 + gg * 8,
                 &Ks[buf][(i2 * 32 + w * 8) * 64]);
        }
    };
    auto stageV = [&](int k0, int buf) {
        if (w < 2) {
            int row = w * 8 + (lane >> 3);
            int gg = (lane & 7) ^ (row & 7);
            gl16(vt + (size_t)(b * DKV + h * 16 + row) * Ss + k0 + gg * 8,
                 &Vs[buf][(w * 8) * 64]);
        }
    };

    float l_lane[4] = {0.f, 0.f, 0.f, 0.f};  // per-lane partial sums (fixed M)
    fx4 oacc = (fx4){0.f, 0.f, 0.f, 0.f};

    stageK(0, 0);
    stageV(0, 0);
    int buf = 0;
    const int qrb = q0 + w * 16 + quad * 4;  // this lane's score-row q base
    const int qmin = q0 + w * 16;

    for (int kb = 0; kb < nkb; ++kb) {
        int k0 = kb * 64;
        __syncthreads();  // drains prefetch vmcnt; prior LDS reads complete
        if (kb + 1 < nkb) { stageK(k0 + 64, buf ^ 1); stageV(k0 + 64, buf ^ 1); }

        // scores: per 16-key tile tt, C[row=quad*4+r][col=key l15]
        fx4 s[4];
#pragma unroll
        for (int tt = 0; tt < 4; ++tt) {
            const u16* kb_ = &Ks[buf][(tt * 16 + l15) * 64];
            bf16x8 kf0 = *(const bf16x8*)(kb_ + ((quad ^ (l15 & 7)) * 8));
            bf16x8 kf1 = *(const bf16x8*)(kb_ + (((quad + 4) ^ (l15 & 7)) * 8));
            fx4 z = (fx4){0.f, 0.f, 0.f, 0.f};
            fx4 a = MFMA16(qf0, kf0, z);
            s[tt] = MFMA16(qf1, kf1, a);
        }

        u32 pw0 = kpb[b * 64 + (k0 >> 5)];
        u32 pw1 = kpb[b * 64 + (k0 >> 5) + 1];
        bool fast = (k0 + 63 <= qmin) & ((pw0 | pw1) == 0u);

        // fixed-M: e = 2^(s*SC2 - 32); softmax shift-invariant, diag score >= 0
        // guarantees dominant e >= 2^-32; masked -> 0 via cndmask (finite s, no NaN)
        float e[4][4];
        if (fast) {
#pragma unroll
            for (int tt = 0; tt < 4; ++tt)
#pragma unroll
                for (int r = 0; r < 4; ++r)
                    e[tt][r] = exp2f(fmaf(s[tt][r], SC2, -32.f));
        } else {
            u32 padb[4];
#pragma unroll
            for (int tt = 0; tt < 4; ++tt)
                padb[tt] = ((tt & 2 ? pw1 : pw0) >> ((tt * 16 + l15) & 31)) & 1u;
#pragma unroll
            for (int r = 0; r < 4; ++r) {
                int qq = qrb + r;
#pragma unroll
                for (int tt = 0; tt < 4; ++tt) {
                    float ee = exp2f(fmaf(s[tt][r], SC2, -32.f));
                    e[tt][r] = (k0 + tt * 16 + l15 <= qq && !padb[tt]) ? ee : 0.f;
                }
            }
        }

#pragma unroll
        for (int r = 0; r < 4; ++r) {
            l_lane[r] += (e[0][r] + e[1][r]) + (e[2][r] + e[3][r]);
            int prow = (quad * 4 + r) * PSTR + l15;
            Ps[w][prow + 0] = bfr(e[0][r]);
            Ps[w][prow + 16] = bfr(e[1][r]);
            Ps[w][prow + 32] = bfr(e[2][r]);
            Ps[w][prow + 48] = bfr(e[3][r]);
        }

        // PV: A=P[m=q l15][k=key], B=V[n=feat l15][k=key]; same-wave LDS, no barrier
#pragma unroll
        for (int hh2 = 0; hh2 < 2; ++hh2) {
            bf16x8 vf = *(const bf16x8*)(&Vs[buf][l15 * 64 + (((quad + 4 * hh2) ^ (l15 & 7)) * 8)]);
            bf16x8 pf = *(const bf16x8*)(&Ps[w][l15 * PSTR + hh2 * 32 + quad * 8]);
            oacc = MFMA16(pf, vf, oacc);
        }
        buf ^= 1;
    }

    // epilogue: row sum reduce (once), then out = O_small[u] replicated x4 (f32)
#pragma unroll
    for (int r = 0; r < 4; ++r) {
        float l_row = rsum16(l_lane[r]);
        float a = oacc[r] / l_row;
        float4 o4 = {a, a, a, a};
        *(float4*)(out + (size_t)(b * Ss + qrb + r) * Dd + h * 64 + l15 * 4) = o4;
    }
}

// ---------------- launch ----------------
extern "C" void kernel_launch(void* const* d_in, const int* in_sizes, int n_in,
                              void* d_out, int out_size, void* d_ws, size_t ws_size,
                              hipStream_t stream) {
    const float* x = (const float*)d_in[0];
    const float* Wq = (const float*)d_in[1];
    const float* Wk = (const float*)d_in[2];
    const float* Wv = (const float*)d_in[3];
    float* out = (float*)d_out;

    char* ws = (char*)d_ws;
    const size_t SZ_XC = (size_t)ROWS * Dd * 2;    // 8 MiB (aliased by krope)
    const size_t SZ_KPB = 4096;
    const size_t SZ_WALL = (size_t)NQKV * Dd * 2;  // 3 MiB (aliased by vtb 2 MiB)
    const size_t SZ_QKV = (size_t)ROWS * NQKV * 2; // 12 MiB

    size_t off = 0;
    u16* xc = (u16*)(ws + off);
    u16* krope = (u16*)(ws + off); off += SZ_XC;   // alias: xc dead after gemm
    u32* kpb = (u32*)(ws + off); off += SZ_KPB;
    u16* wAll = (u16*)(ws + off);
    u16* vtb = (u16*)(ws + off); off += SZ_WALL;   // alias: wAll dead after gemm
    u16* qkv = (u16*)(ws + off); off += SZ_QKV;
    (void)ws_size; (void)in_sizes; (void)n_in; (void)out_size;

    hipMemsetAsync(kpb, 0, 2 * 64 * 4, stream);
    pre_kernel<<<5632, 256, 0, stream>>>(x, Wq, Wk, Wv, xc, kpb, wAll);
    gemm_qkv<<<dim3(NQKV / 128, ROWS / 128), 256, 0, stream>>>(xc, wAll, qkv);
    post_kernel<<<5120, 256, 0, stream>>>(qkv, krope, vtb);
    attn_kernel<<<1024, 256, 0, stream>>>(qkv, krope, vtb, kpb, out);
}